// Round 12
// baseline (2501.908 us; speedup 1.0000x reference)
//
#include <hip/hip_runtime.h>
#include <hip/hip_bf16.h>

#define NE 800000
#define NN 50000
#define NG 16
#define ETOT (NE + NN)
#define SL 64  // bn accumulation slots

typedef unsigned short u16;
typedef __attribute__((ext_vector_type(8))) short short8;
typedef __attribute__((ext_vector_type(4))) float float4v;

__device__ __forceinline__ float b2f(u16 u) {
  return __uint_as_float(((unsigned)u) << 16);
}
__device__ __forceinline__ u16 f2b(float f) {
  __hip_bfloat16 b = __float2bfloat16(f);
  return *(u16*)&b;
}
__device__ __forceinline__ void cv8(uint4 v, float* o) {
  o[0] = __uint_as_float(v.x << 16);
  o[1] = __uint_as_float(v.x & 0xFFFF0000u);
  o[2] = __uint_as_float(v.y << 16);
  o[3] = __uint_as_float(v.y & 0xFFFF0000u);
  o[4] = __uint_as_float(v.z << 16);
  o[5] = __uint_as_float(v.z & 0xFFFF0000u);
  o[6] = __uint_as_float(v.w << 16);
  o[7] = __uint_as_float(v.w & 0xFFFF0000u);
}
__device__ __forceinline__ unsigned pk2(float a, float b) {
  return (unsigned)f2b(a) | ((unsigned)f2b(b) << 16);
}
__device__ __forceinline__ unsigned f2key(float f) {
  unsigned u = __float_as_uint(f);
  return (u & 0x80000000u) ? ~u : (u | 0x80000000u);
}
__device__ __forceinline__ float key2f(unsigned k) {
  unsigned u = (k & 0x80000000u) ? (k ^ 0x80000000u) : ~k;
  return __uint_as_float(u);
}
__device__ __forceinline__ int plaus(unsigned h) {
  unsigned eh = (h >> 7) & 0xFF;
  return (h == 0) || (eh >= 100 && eh <= 140);
}

// ========== D1: zero accumulator region + dtype detect (block 0) ==========
__global__ __launch_bounds__(256) void k_init(uint4* __restrict__ zbase, int zcnt16,
                                              const unsigned* __restrict__ a,
                                              const unsigned* __restrict__ b,
                                              const unsigned* __restrict__ c,
                                              int* __restrict__ flags) {
  uint4 z = {0, 0, 0, 0};
  for (int i = blockIdx.x * 256 + threadIdx.x; i < zcnt16; i += gridDim.x * 256)
    zbase[i] = z;
  if (blockIdx.x != 0) return;
  __shared__ int cnt[3];
  if (threadIdx.x < 3) cnt[threadIdx.x] = 0;
  __syncthreads();
  const unsigned* arr[3] = {a, b, c};
  for (int k = 0; k < 3; k++) {
    int ok = 0;
    for (int i = threadIdx.x; i < 4096; i += 256) {
      unsigned w = arr[k][i];
      ok += (plaus(w & 0xFFFFu) && plaus(w >> 16)) ? 1 : 0;
    }
    atomicAdd(&cnt[k], ok);
  }
  __syncthreads();
  if (threadIdx.x == 0) {
    int f0 = cnt[0] > 2048, f1 = cnt[1] > 2048, f2 = cnt[2] > 2048;
    flags[0] = f0;
    flags[1] = f1;
    flags[2] = f2;
    flags[3] = f0 && f1 && f2;
  }
}

// ========== D2: hist + colsum + (last block) prefix scan ==========
__global__ __launch_bounds__(256) void k_histscan(const int* __restrict__ ei,
                                                  const void* __restrict__ ea,
                                                  int* __restrict__ deg,
                                                  float* __restrict__ sums,
                                                  int* __restrict__ start,
                                                  int* __restrict__ cursor,
                                                  int* __restrict__ done) {
  __shared__ float ls[256];
  __shared__ int ps[256];
  // local eb detect: sample 256 words of ea
  {
    unsigned w = ((const unsigned*)ea)[threadIdx.x];
    int ok = (plaus(w & 0xFFFFu) && plaus(w >> 16)) ? 1 : 0;
    ps[threadIdx.x] = ok;
  }
  __syncthreads();
  int cnt = 0;
  if (threadIdx.x == 0) {
    for (int i = 0; i < 256; i++) cnt += ps[i];
    ps[0] = cnt;
  }
  __syncthreads();
  bool eb = ps[0] > 192;
  __syncthreads();

  int gt = blockIdx.x * 256 + threadIdx.x;
  if (gt < ETOT) {
    int dst = (gt < NE) ? ei[NE + gt] : gt - NE;
    atomicAdd(&deg[dst], 1);
  }
  int col = gt & 15;
  int row = gt >> 4;
  int rstride = (gridDim.x * 256) >> 4;
  float s = 0.f;
  if (eb) {
    const u16* p = (const u16*)ea;
    for (int e = row; e < NE; e += rstride) s += b2f(p[(size_t)e * 16 + col]);
  } else {
    const float* p = (const float*)ea;
    for (int e = row; e < NE; e += rstride) s += p[(size_t)e * 16 + col];
  }
  ls[threadIdx.x] = s;
  __syncthreads();
  if (threadIdx.x < 16) {
    float t = 0.f;
    for (int i = threadIdx.x; i < 256; i += 16) t += ls[i];
    atomicAdd(&sums[threadIdx.x], t);
  }
  // last block: prefix scan over deg (atomic reads for visibility)
  __threadfence();
  __syncthreads();
  __shared__ int lastblk;
  if (threadIdx.x == 0) lastblk = (atomicAdd(done, 1) == (int)gridDim.x - 1);
  __syncthreads();
  if (!lastblk) return;
  int t = threadIdx.x;
  const int CH = (NN + 255) / 256;
  int b0 = t * CH;
  int bend = min(b0 + CH, NN);
  int acc = 0;
  for (int i = b0; i < bend; i++) acc += atomicAdd(&deg[i], 0);
  ps[t] = acc;
  __syncthreads();
  for (int ofs = 1; ofs < 256; ofs <<= 1) {
    int v = (t >= ofs) ? ps[t - ofs] : 0;
    __syncthreads();
    ps[t] += v;
    __syncthreads();
  }
  int run = (t == 0) ? 0 : ps[t - 1];
  for (int i = b0; i < bend; i++) {
    start[i] = run;
    cursor[i] = run;
    run += atomicAdd(&deg[i], 0);
  }
  if (t == 255) start[NN] = run;
}

// ========== D3: CSR build (payload bf16) || lin3 layer-1 ==========
// blocks [0, eg): build; blocks [eg, eg+375): lin3 L1 (wset*125 + tile).
template <int K, int N>
__global__ __launch_bounds__(256) void k_buildlin1(
    int eg, int tier3,
    const int* __restrict__ ei, const void* __restrict__ eattr,
    const int* __restrict__ flg, const float* __restrict__ mean_sums,
    int* __restrict__ cursor, int* __restrict__ csr_src,
    u16* __restrict__ ea16, uint2* __restrict__ csr,
    const void* __restrict__ xin,
    const void* W0, const void* W1, const void* W2,
    const void* b0, const void* b1, const void* b2,
    u16* __restrict__ o0, u16* __restrict__ o1, u16* __restrict__ o2, int M) {
  constexpr int TM = 32;
  constexpr size_t SMV = (size_t)(K * N + TM * (K + 1) + N) * 4;
  constexpr size_t SMM = (size_t)K * N * 2;
  __shared__ __align__(16) char smem[SMV > SMM ? SMV : SMM];

  if ((int)blockIdx.x < eg) {
    // ---- CSR build ----
    int e = blockIdx.x * 256 + threadIdx.x;
    if (e >= ETOT) return;
    bool eb = flg[2] != 0;
    int src, dst;
    if (e < NE) { src = ei[e]; dst = ei[NE + e]; } else { src = dst = e - NE; }
    if (tier3) {
      int pos = atomicAdd(&cursor[dst], 1);
      uint2 r; r.x = (unsigned)src; r.y = (unsigned)e;
      csr[pos] = r;
      return;
    }
    float rec[16];
    if (e < NE) {
      if (eb) {
        const uint4* q = (const uint4*)((const u16*)eattr + (size_t)e * 16);
        cv8(q[0], rec);
        cv8(q[1], rec + 8);
      } else {
        const float* q = (const float*)eattr + (size_t)e * 16;
#pragma unroll
        for (int k = 0; k < 16; k++) rec[k] = q[k];
      }
    } else {
#pragma unroll
      for (int k = 0; k < 16; k++) rec[k] = mean_sums[k] * (1.0f / NE);
    }
    int pos = atomicAdd(&cursor[dst], 1);
    csr_src[pos] = src;
    u16 rb[16];
#pragma unroll
    for (int k = 0; k < 16; k++) rb[k] = f2b(rec[k]);
    uint4* dp = (uint4*)(ea16 + (size_t)pos * 16);
    dp[0] = *(uint4*)rb;
    dp[1] = *(uint4*)(rb + 8);
    return;
  }
  // ---- lin3 L1 ----
  int lidx = blockIdx.x - eg;      // 0..374
  int wset = lidx / 125;
  int tile = lidx % 125;
  bool wb = flg[1] != 0;
  bool xb = flg[0] != 0;
  const void* W = wset == 0 ? W0 : (wset == 1 ? W1 : W2);
  const void* bb = wset == 0 ? b0 : (wset == 1 ? b1 : b2);
  u16* out = wset == 0 ? o0 : (wset == 1 ? o1 : o2);

  if (wb && xb) {
    constexpr int CT = N / 16;
    constexpr int WPC = 4 / CT;
    constexpr int KK = K / 32;
    const u16* Wp = (const u16*)W;
    const u16* bp = (const u16*)bb;
    const u16* xp = (const u16*)xin;
    u16* Wl = (u16*)smem;
    for (int i = threadIdx.x; i < K * N / 8; i += 256)
      *(uint4*)&Wl[i * 8] = ((const uint4*)Wp)[i];
    __syncthreads();
    int wave = threadIdx.x >> 6;
    int lane = threadIdx.x & 63;
    int col = lane & 15;
    int quad = lane >> 4;
    int ct = wave % CT;
    int rt_off = wave / CT;
    short8 bfrag[KK];
#pragma unroll
    for (int kk = 0; kk < KK; kk++) {
      short8 t;
#pragma unroll
      for (int j = 0; j < 8; j++)
        t[j] = (short)Wl[(kk * 32 + quad * 8 + j) * N + ct * 16 + col];
      bfrag[kk] = t;
    }
    float bias = b2f(bp[ct * 16 + col]);
    constexpr int RPB = 25;
    int rt0 = tile * RPB;
    for (int i = rt_off; i < RPB; i += WPC) {
      int rt = rt0 + i;
      int row = rt * 16 + col;
      float4v acc = {0.f, 0.f, 0.f, 0.f};
#pragma unroll
      for (int kk = 0; kk < KK; kk++) {
        short8 afrag = *(const short8*)(xp + (size_t)row * K + kk * 32 + quad * 8);
        acc = __builtin_amdgcn_mfma_f32_16x16x32_bf16(afrag, bfrag[kk], acc, 0, 0, 0);
      }
#pragma unroll
      for (int r = 0; r < 4; r++) {
        int orow = rt * 16 + quad * 4 + r;
        out[(size_t)orow * N + ct * 16 + col] = f2b(acc[r] + bias);
      }
    }
  } else {
    constexpr int CPT = (N >= 64) ? 8 : 4;
    constexpr int TCOLS = N / CPT;
    float* Wf = (float*)smem;
    float* xs = Wf + K * N;
    float* bfs = xs + TM * (K + 1);
    int tid = threadIdx.x;
    if (wb) {
      const u16* Wp = (const u16*)W;
      for (int i = tid; i < K * N / 8; i += 256) {
        float t[8];
        cv8(*(const uint4*)(Wp + i * 8), t);
#pragma unroll
        for (int q = 0; q < 8; q++) Wf[i * 8 + q] = t[q];
      }
    } else {
      const float* Wp = (const float*)W;
      for (int i = tid; i < K * N / 4; i += 256) {
        float4 v = *(const float4*)(Wp + i * 4);
        Wf[i * 4 + 0] = v.x; Wf[i * 4 + 1] = v.y;
        Wf[i * 4 + 2] = v.z; Wf[i * 4 + 3] = v.w;
      }
    }
    if (tid < N) bfs[tid] = wb ? b2f(((const u16*)bb)[tid]) : ((const float*)bb)[tid];
    int tc = tid % TCOLS, tr = tid / TCOLS;
    for (int r0 = tile * TM; r0 < M; r0 += 125 * TM) {
      __syncthreads();
      if (xb) {
        const u16* xp = (const u16*)xin;
        for (int i = tid; i < TM * K / 8; i += 256) {
          int lr = i / (K / 8), lc = (i % (K / 8)) * 8;
          int gr = r0 + lr;
          float t[8] = {0, 0, 0, 0, 0, 0, 0, 0};
          if (gr < M) cv8(*(const uint4*)(xp + (size_t)gr * K + lc), t);
#pragma unroll
          for (int q = 0; q < 8; q++) xs[lr * (K + 1) + lc + q] = t[q];
        }
      } else {
        const float* xp = (const float*)xin;
        for (int i = tid; i < TM * K / 4; i += 256) {
          int lr = i / (K / 4), lc = (i % (K / 4)) * 4;
          int gr = r0 + lr;
          float4 v = {0, 0, 0, 0};
          if (gr < M) v = *(const float4*)(xp + (size_t)gr * K + lc);
          xs[lr * (K + 1) + lc + 0] = v.x;
          xs[lr * (K + 1) + lc + 1] = v.y;
          xs[lr * (K + 1) + lc + 2] = v.z;
          xs[lr * (K + 1) + lc + 3] = v.w;
        }
      }
      __syncthreads();
      float acc[CPT];
#pragma unroll
      for (int c = 0; c < CPT; c++) acc[c] = bfs[tc * CPT + c];
#pragma unroll 4
      for (int k = 0; k < K; k++) {
        float xv = xs[tr * (K + 1) + k];
#pragma unroll
        for (int c = 0; c < CPT; c++) acc[c] += xv * Wf[k * N + tc * CPT + c];
      }
      int gr = r0 + tr;
      if (gr < M) {
        u16* op = out + (size_t)gr * N + tc * CPT;
        if constexpr (CPT == 8) {
          uint4 o;
          o.x = pk2(acc[0], acc[1]); o.y = pk2(acc[2], acc[3]);
          o.z = pk2(acc[4], acc[5]); o.w = pk2(acc[6], acc[7]);
          *(uint4*)op = o;
        } else {
          uint2 o;
          o.x = pk2(acc[0], acc[1]); o.y = pk2(acc[2], acc[3]);
          *(uint2*)op = o;
        }
      }
    }
  }
}

// ==== standalone lin3 (layer 2) ====
template <int K, int N>
__global__ __launch_bounds__(256) void k_lin3b(
    const void* __restrict__ xin, const int* __restrict__ flg,
    const void* W0, const void* W1, const void* W2,
    const void* b0, const void* b1, const void* b2,
    u16* __restrict__ o0, u16* __restrict__ o1, u16* __restrict__ o2, int M) {
  constexpr int TM = 32;
  constexpr size_t SMV = (size_t)(K * N + TM * (K + 1) + N) * 4;
  constexpr size_t SMM = (size_t)K * N * 2;
  __shared__ __align__(16) char smem[SMV > SMM ? SMV : SMM];
  bool wb = flg[1] != 0;
  const void* W = blockIdx.y == 0 ? W0 : (blockIdx.y == 1 ? W1 : W2);
  const void* bb = blockIdx.y == 0 ? b0 : (blockIdx.y == 1 ? b1 : b2);
  u16* out = blockIdx.y == 0 ? o0 : (blockIdx.y == 1 ? o1 : o2);
  // x is always internal bf16 here
  if (wb) {
    constexpr int CT = N / 16;
    constexpr int WPC = 4 / CT;
    constexpr int KK = K / 32;
    const u16* Wp = (const u16*)W;
    const u16* bp = (const u16*)bb;
    const u16* xp = (const u16*)xin;
    u16* Wl = (u16*)smem;
    for (int i = threadIdx.x; i < K * N / 8; i += 256)
      *(uint4*)&Wl[i * 8] = ((const uint4*)Wp)[i];
    __syncthreads();
    int wave = threadIdx.x >> 6;
    int lane = threadIdx.x & 63;
    int col = lane & 15;
    int quad = lane >> 4;
    int ct = wave % CT;
    int rt_off = wave / CT;
    short8 bfrag[KK];
#pragma unroll
    for (int kk = 0; kk < KK; kk++) {
      short8 t;
#pragma unroll
      for (int j = 0; j < 8; j++)
        t[j] = (short)Wl[(kk * 32 + quad * 8 + j) * N + ct * 16 + col];
      bfrag[kk] = t;
    }
    float bias = b2f(bp[ct * 16 + col]);
    constexpr int RPB = 25;
    int rt0 = blockIdx.x * RPB;
    for (int i = rt_off; i < RPB; i += WPC) {
      int rt = rt0 + i;
      int row = rt * 16 + col;
      float4v acc = {0.f, 0.f, 0.f, 0.f};
#pragma unroll
      for (int kk = 0; kk < KK; kk++) {
        short8 afrag = *(const short8*)(xp + (size_t)row * K + kk * 32 + quad * 8);
        acc = __builtin_amdgcn_mfma_f32_16x16x32_bf16(afrag, bfrag[kk], acc, 0, 0, 0);
      }
#pragma unroll
      for (int r = 0; r < 4; r++) {
        int orow = rt * 16 + quad * 4 + r;
        out[(size_t)orow * N + ct * 16 + col] = f2b(acc[r] + bias);
      }
    }
  } else {
    constexpr int CPT = 4;
    constexpr int TCOLS = N / CPT;
    float* Wf = (float*)smem;
    float* xs = Wf + K * N;
    float* bfs = xs + TM * (K + 1);
    int tid = threadIdx.x;
    {
      const float* Wp = (const float*)W;
      for (int i = tid; i < K * N / 4; i += 256) {
        float4 v = *(const float4*)(Wp + i * 4);
        Wf[i * 4 + 0] = v.x; Wf[i * 4 + 1] = v.y;
        Wf[i * 4 + 2] = v.z; Wf[i * 4 + 3] = v.w;
      }
    }
    if (tid < N) bfs[tid] = ((const float*)bb)[tid];
    int tc = tid % TCOLS, tr = tid / TCOLS;
    for (int r0 = blockIdx.x * TM; r0 < M; r0 += gridDim.x * TM) {
      __syncthreads();
      const u16* xp = (const u16*)xin;
      for (int i = tid; i < TM * K / 8; i += 256) {
        int lr = i / (K / 8), lc = (i % (K / 8)) * 8;
        int gr = r0 + lr;
        float t[8] = {0, 0, 0, 0, 0, 0, 0, 0};
        if (gr < M) cv8(*(const uint4*)(xp + (size_t)gr * K + lc), t);
#pragma unroll
        for (int q = 0; q < 8; q++) xs[lr * (K + 1) + lc + q] = t[q];
      }
      __syncthreads();
      float acc[CPT];
#pragma unroll
      for (int c = 0; c < CPT; c++) acc[c] = bfs[tc * CPT + c];
#pragma unroll 4
      for (int k = 0; k < K; k++) {
        float xv = xs[tr * (K + 1) + k];
#pragma unroll
        for (int c = 0; c < CPT; c++) acc[c] += xv * Wf[k * N + tc * CPT + c];
      }
      int gr = r0 + tr;
      if (gr < M) {
        uint2 o;
        o.x = pk2(acc[0], acc[1]); o.y = pk2(acc[2], acc[3]);
        *(uint2*)(out + (size_t)gr * N + tc * CPT) = o;
      }
    }
  }
}

// ===== payload dots =====
__device__ __forceinline__ float dot16b(const u16* __restrict__ p,
                                        const float* __restrict__ W) {
  float ea[16];
  const uint4* q = (const uint4*)p;
  cv8(q[0], ea);
  cv8(q[1], ea + 8);
  float s = 0.f;
#pragma unroll
  for (int k = 0; k < 16; k++) s += ea[k] * W[k];
  return s;
}
__device__ __forceinline__ float dot16f(const float* __restrict__ q,
                                        const float* __restrict__ W) {
  float s = 0.f;
#pragma unroll
  for (int k = 0; k < 16; k++) s += q[k] * W[k];
  return s;
}

// ===== bn tail: block partial sums -> slotted atomics; last block finalizes =====
template <int D>
__device__ __forceinline__ void bn_tail(float val, int node_ok,
                                        float* __restrict__ slots_s,
                                        float* __restrict__ slots_q,
                                        float* __restrict__ bnsum,
                                        float* __restrict__ bnsq,
                                        int* __restrict__ done) {
  __shared__ float ps[256], qs[256];
  int tid = threadIdx.x;
  ps[tid] = node_ok ? val : 0.f;
  qs[tid] = node_ok ? val * val : 0.f;
  __syncthreads();
  if (tid < D) {
    float s = 0.f, q = 0.f;
    for (int i = tid; i < 256; i += D) { s += ps[i]; q += qs[i]; }
    int slot = blockIdx.x & (SL - 1);
    atomicAdd(&slots_s[slot * D + tid], s);
    atomicAdd(&slots_q[slot * D + tid], q);
  }
  __threadfence();
  __syncthreads();
  __shared__ int lastblk;
  if (tid == 0) lastblk = (atomicAdd(done, 1) == (int)gridDim.x - 1);
  __syncthreads();
  if (!lastblk) return;
  if (tid < D) {
    float s = 0.f, q = 0.f;
    for (int sl = 0; sl < SL; sl++) {
      s += atomicAdd(&slots_s[sl * D + tid], 0.f);
      q += atomicAdd(&slots_q[sl * D + tid], 0.f);
    }
    bnsum[tid] = s;
    bnsq[tid] = q;
  }
}

// ===== D4/D7: fused attention + softmax gather-reduce + bn tail =====
template <int H, int C>
__global__ __launch_bounds__(256) void k_fusedp(
    const int* __restrict__ start, const int* __restrict__ csr_src,
    const u16* __restrict__ pay, const int* __restrict__ flg,
    const u16* __restrict__ xl, const u16* __restrict__ xr,
    const void* We, const void* att, u16* __restrict__ agg,
    float* __restrict__ slots_s, float* __restrict__ slots_q,
    float* __restrict__ bnsum, float* __restrict__ bnsq,
    int* __restrict__ done) {
  constexpr int D = H * C;
  constexpr int NPW = 64 / D;
  bool wb = flg[1] != 0;
  int lane = threadIdx.x & 63;
  int ch = lane % D;
  float Wreg[16];
  if (wb) {
    const u16* Wp = (const u16*)We;
#pragma unroll
    for (int k = 0; k < 16; k++) Wreg[k] = b2f(Wp[k * D + ch]);
  } else {
    const float* Wp = (const float*)We;
#pragma unroll
    for (int k = 0; k < 16; k++) Wreg[k] = Wp[k * D + ch];
  }
  float attv = wb ? b2f(((const u16*)att)[ch]) : ((const float*)att)[ch];
  int wid = (blockIdx.x * 256 + threadIdx.x) >> 6;
  int node = wid * NPW + lane / D;   // grids exact: node < NN always
  int s0 = start[node], s1 = start[node + 1];
  float xrv = b2f(xr[(size_t)node * D + ch]);
  float ssum = 0.f, acc = 0.f;

  if constexpr (NPW == 1) {
    int p = s0;
    for (; p + 1 < s1; p += 2) {
      int c0 = csr_src[p], c1 = csr_src[p + 1];
      float xlv0 = b2f(xl[(size_t)c0 * D + ch]);
      float xlv1 = b2f(xl[(size_t)c1 * D + ch]);
      float ev0 = dot16b(pay + (size_t)p * 16, Wreg);
      float ev1 = dot16b(pay + (size_t)(p + 1) * 16, Wreg);
      float mv0 = xlv0 + xrv + ev0;
      float mv1 = xlv1 + xrv + ev1;
      mv0 = (mv0 > 0.f) ? mv0 : 0.2f * mv0;
      mv1 = (mv1 > 0.f) ? mv1 : 0.2f * mv1;
      float t0 = mv0 * attv, t1 = mv1 * attv;
#pragma unroll
      for (int mk = 1; mk <= 16; mk <<= 1) {
        t0 += __shfl_xor(t0, mk, 64);
        t1 += __shfl_xor(t1, mk, 64);
      }
      float ex0 = __expf(t0);
      float ex1 = __expf(t1);
      ssum += ex0 + ex1;
      acc += ex0 * xlv0 + ex1 * xlv1;
    }
    if (p < s1) {
      int c0 = csr_src[p];
      float xlv = b2f(xl[(size_t)c0 * D + ch]);
      float ev = dot16b(pay + (size_t)p * 16, Wreg);
      float mv = xlv + xrv + ev;
      mv = (mv > 0.f) ? mv : 0.2f * mv;
      float t = mv * attv;
#pragma unroll
      for (int mk = 1; mk <= 16; mk <<= 1) t += __shfl_xor(t, mk, 64);
      float ex = __expf(t);
      ssum += ex;
      acc += ex * xlv;
    }
  } else {
    int deg = s1 - s0;
    int last = s1 - 1;
    int degmax = max(deg, __shfl_xor(deg, 32, 64));
    for (int i = 0; i < degmax; i += 2) {
      int p0 = min(s0 + i, last), p1 = min(s0 + i + 1, last);
      bool a0 = i < deg, a1 = i + 1 < deg;
      int c0 = csr_src[p0], c1 = csr_src[p1];
      float xlv0 = b2f(xl[(size_t)c0 * D + ch]);
      float xlv1 = b2f(xl[(size_t)c1 * D + ch]);
      float ev0 = dot16b(pay + (size_t)p0 * 16, Wreg);
      float ev1 = dot16b(pay + (size_t)p1 * 16, Wreg);
      float mv0 = xlv0 + xrv + ev0;
      float mv1 = xlv1 + xrv + ev1;
      mv0 = (mv0 > 0.f) ? mv0 : 0.2f * mv0;
      mv1 = (mv1 > 0.f) ? mv1 : 0.2f * mv1;
      float t0 = mv0 * attv, t1 = mv1 * attv;
#pragma unroll
      for (int mk = 1; mk <= 16; mk <<= 1) {
        t0 += __shfl_xor(t0, mk, 64);
        t1 += __shfl_xor(t1, mk, 64);
      }
      float ex0 = a0 ? __expf(t0) : 0.f;
      float ex1 = a1 ? __expf(t1) : 0.f;
      ssum += ex0 + ex1;
      acc += ex0 * xlv0 + ex1 * xlv1;
    }
  }
  float val = acc / (ssum + 1e-16f);
  agg[(size_t)node * D + ch] = f2b(val);
  bn_tail<D>(val, 1, slots_s, slots_q, bnsum, bnsq, done);
}

// ===== tier-3 eid-indirect fused (+ bn tail) =====
template <int H, int C>
__global__ __launch_bounds__(256) void k_fusedg(
    const int* __restrict__ start, const uint2* __restrict__ csr,
    const void* __restrict__ eattr, const int* __restrict__ flg,
    const float* __restrict__ mean_sums,
    const u16* __restrict__ xl, const u16* __restrict__ xr,
    const void* We, const void* att, u16* __restrict__ agg,
    float* __restrict__ slots_s, float* __restrict__ slots_q,
    float* __restrict__ bnsum, float* __restrict__ bnsq,
    int* __restrict__ done) {
  constexpr int D = H * C;
  constexpr int NPW = 64 / D;
  bool wb = flg[1] != 0;
  bool eb = flg[2] != 0;
  int lane = threadIdx.x & 63;
  int ch = lane % D;
  float Wreg[16];
  if (wb) {
    const u16* Wp = (const u16*)We;
#pragma unroll
    for (int k = 0; k < 16; k++) Wreg[k] = b2f(Wp[k * D + ch]);
  } else {
    const float* Wp = (const float*)We;
#pragma unroll
    for (int k = 0; k < 16; k++) Wreg[k] = Wp[k * D + ch];
  }
  float attv = wb ? b2f(((const u16*)att)[ch]) : ((const float*)att)[ch];
  float ev_self = 0.f;
#pragma unroll
  for (int k = 0; k < 16; k++) ev_self += mean_sums[k] * (1.0f / NE) * Wreg[k];
  int wid = (blockIdx.x * 256 + threadIdx.x) >> 6;
  int node = wid * NPW + lane / D;
  int s0 = start[node], s1 = start[node + 1];
  int deg = s1 - s0;
  int last = s1 - 1;
  int degmax = deg;
  if constexpr (NPW == 2) degmax = max(deg, __shfl_xor(deg, 32, 64));
  float xrv = b2f(xr[(size_t)node * D + ch]);
  float ssum = 0.f, acc = 0.f;
  for (int i = 0; i < degmax; i += 2) {
    uint2 cr0 = csr[min(s0 + i, last)];
    uint2 cr1 = csr[min(s0 + i + 1, last)];
    bool a0 = i < deg, a1 = i + 1 < deg;
    float xlv0 = b2f(xl[(size_t)cr0.x * D + ch]);
    float xlv1 = b2f(xl[(size_t)cr1.x * D + ch]);
    float ev0 = cr0.y < NE ? (eb ? dot16b((const u16*)eattr + (size_t)cr0.y * 16, Wreg)
                                 : dot16f((const float*)eattr + (size_t)cr0.y * 16, Wreg))
                           : ev_self;
    float ev1 = cr1.y < NE ? (eb ? dot16b((const u16*)eattr + (size_t)cr1.y * 16, Wreg)
                                 : dot16f((const float*)eattr + (size_t)cr1.y * 16, Wreg))
                           : ev_self;
    float mv0 = xlv0 + xrv + ev0;
    float mv1 = xlv1 + xrv + ev1;
    mv0 = (mv0 > 0.f) ? mv0 : 0.2f * mv0;
    mv1 = (mv1 > 0.f) ? mv1 : 0.2f * mv1;
    float t0 = mv0 * attv, t1 = mv1 * attv;
#pragma unroll
    for (int mk = 1; mk <= 16; mk <<= 1) {
      t0 += __shfl_xor(t0, mk, 64);
      t1 += __shfl_xor(t1, mk, 64);
    }
    float ex0 = a0 ? __expf(t0) : 0.f;
    float ex1 = a1 ? __expf(t1) : 0.f;
    ssum += ex0 + ex1;
    acc += ex0 * xlv0 + ex1 * xlv1;
  }
  float val = acc / (ssum + 1e-16f);
  agg[(size_t)node * D + ch] = f2b(val);
  bn_tail<D>(val, 1, slots_s, slots_q, bnsum, bnsq, done);
}

// ========== D5: batch-norm apply + skip + ELU (layer 1) ==========
template <int D>
__global__ __launch_bounds__(256) void k_bnapply(const u16* __restrict__ agg,
                                                 const u16* __restrict__ hp,
                                                 const float* __restrict__ sum,
                                                 const float* __restrict__ sq,
                                                 const void* g, const void* b,
                                                 const int* __restrict__ flg,
                                                 u16* __restrict__ out, int M) {
  bool wb = flg[1] != 0;
  int idx = blockIdx.x * 256 + threadIdx.x;
  if (idx >= M * D) return;
  int c = idx & (D - 1);
  float gc = wb ? b2f(((const u16*)g)[c]) : ((const float*)g)[c];
  float bc = wb ? b2f(((const u16*)b)[c]) : ((const float*)b)[c];
  float mu = sum[c] * (1.f / M);
  float var = fmaxf(sq[c] * (1.f / M) - mu * mu, 0.f);
  float sc = rsqrtf(var + 1e-5f) * gc;
  float v = (b2f(agg[idx]) - mu) * sc + bc + b2f(hp[idx]);
  v = v > 0.f ? v : expm1f(v);
  out[idx] = f2b(v);
}

// ========== D8: BN2-apply + ELU + pool + (last block) finalize ==========
__global__ __launch_bounds__(256) void k_poolall(
    const u16* __restrict__ agg2, const u16* __restrict__ hp2,
    const float* __restrict__ sum, const float* __restrict__ sq,
    const void* g, const void* b, const int* __restrict__ flg,
    const int* __restrict__ batch,
    float* __restrict__ pool_sum, unsigned* __restrict__ pool_maxk,
    float* __restrict__ pool_cnt, int* __restrict__ done_cnt,
    void* __restrict__ out) {
  bool wb = flg[1] != 0;
  int c = threadIdx.x & 31;
  int rg = threadIdx.x >> 5;
  float gc = wb ? b2f(((const u16*)g)[c]) : ((const float*)g)[c];
  float bc = wb ? b2f(((const u16*)b)[c]) : ((const float*)b)[c];
  float mu = sum[c] * (1.f / NN);
  float var = fmaxf(sq[c] * (1.f / NN) - mu * mu, 0.f);
  float scl = rsqrtf(var + 1e-5f) * gc;
  float sh = bc - mu * scl;

  const int NPB = 256;
  int n0 = blockIdx.x * NPB;
  int nend = min(n0 + NPB, NN);
  int cur = -1;
  float s = 0.f, mx = 0.f;
  int cnt = 0;
  for (int n = n0 + rg; n < nend; n += 8) {
    int gi = batch[n];
    float v = b2f(agg2[(size_t)n * 32 + c]) * scl + sh + b2f(hp2[(size_t)n * 32 + c]);
    v = v > 0.f ? v : expm1f(v);
    if (gi != cur) {
      if (cur >= 0) {
        atomicAdd(&pool_sum[cur * 32 + c], s);
        atomicMax(&pool_maxk[cur * 32 + c], f2key(mx));
        if (c == 0) atomicAdd(&pool_cnt[cur], (float)cnt);
      }
      cur = gi; s = 0.f; mx = -INFINITY; cnt = 0;
    }
    s += v;
    mx = fmaxf(mx, v);
    cnt++;
  }
  if (cur >= 0) {
    atomicAdd(&pool_sum[cur * 32 + c], s);
    atomicMax(&pool_maxk[cur * 32 + c], f2key(mx));
    if (c == 0) atomicAdd(&pool_cnt[cur], (float)cnt);
  }
  __threadfence();
  __syncthreads();
  __shared__ int lastblk;
  if (threadIdx.x == 0) lastblk = (atomicAdd(done_cnt, 1) == (int)gridDim.x - 1);
  __syncthreads();
  if (!lastblk) return;
  bool ob = flg[3] != 0;
  for (int idx = threadIdx.x; idx < NG * 64; idx += 256) {
    int gi = idx / 64, cc = idx % 64;
    float cntv = atomicAdd(&pool_cnt[gi], 0.f);
    float val;
    if (cc < 32) val = atomicAdd(&pool_sum[gi * 32 + cc], 0.f) / fmaxf(cntv, 1.f);
    else {
      unsigned k = atomicMax(&pool_maxk[gi * 32 + (cc - 32)], 0u);
      val = cntv > 0.f ? key2f(k) : 0.f;
    }
    if (ob) ((u16*)out)[idx] = f2b(val);
    else ((float*)out)[idx] = val;
  }
}

extern "C" void kernel_launch(void* const* d_in, const int* in_sizes, int n_in,
                              void* d_out, int out_size, void* d_ws, size_t ws_size,
                              hipStream_t stream) {
  (void)in_sizes; (void)n_in; (void)out_size;
  const void* x     = d_in[0];
  const int*  ei    = (const int*)d_in[1];
  const void* eattr = d_in[2];
  const int*  batch = (const int*)d_in[3];
  const void* skip1_W = d_in[4];
  const void* skip1_b = d_in[5];
  const void* c1_Wl = d_in[6];
  const void* c1_bl = d_in[7];
  const void* c1_Wr = d_in[8];
  const void* c1_br = d_in[9];
  const void* c1_We = d_in[10];
  const void* c1_att = d_in[11];
  const void* bn1_g = d_in[13];
  const void* bn1_b = d_in[14];
  const void* skip2_W = d_in[15];
  const void* skip2_b = d_in[16];
  const void* c2_Wl = d_in[17];
  const void* c2_bl = d_in[18];
  const void* c2_Wr = d_in[19];
  const void* c2_br = d_in[20];
  const void* c2_We = d_in[21];
  const void* c2_att = d_in[22];
  const void* bn2_g = d_in[24];
  const void* bn2_b = d_in[25];

  float* ws = (float*)d_ws;
  size_t off = 0;
  auto alloc = [&](size_t nfl) {
    float* p = ws + off;
    off += (nfl + 15) & ~(size_t)15;
    return p;
  };
  // ---- zero-initialized region ----
  int*   flags      = (int*)alloc(16);
  float* mean_sums  = alloc(16);
  int*   deg        = (int*)alloc(NN);
  float* slots_s1   = alloc(SL * 64);
  float* slots_q1   = alloc(SL * 64);
  float* slots_s2   = alloc(SL * 32);
  float* slots_q2   = alloc(SL * 32);
  float* bnsum1     = alloc(64);
  float* bnsq1      = alloc(64);
  float* bnsum2     = alloc(32);
  float* bnsq2      = alloc(32);
  float* pool_cnt   = alloc(NG);
  float* pool_sum   = alloc(NG * 32);
  unsigned* pool_maxk = (unsigned*)alloc(NG * 32);
  int*   done_hs    = (int*)alloc(16);
  int*   done_f1    = (int*)alloc(16);
  int*   done_f2    = (int*)alloc(16);
  int*   done_pool  = (int*)alloc(16);
  size_t zcnt16 = (off * sizeof(float)) / 16;  // uint4 count (allocs 64B-granular)
  size_t zoff = off;

  // ---- tier 2 layout (bf16 payload in CSR order, ~57 MB) ----
  int* start   = (int*)alloc(NN + 1);
  int* cursor  = (int*)alloc(NN);
  int* csr_src = (int*)alloc(ETOT);
  u16* ea16    = (u16*)alloc((size_t)ETOT * 8);
  uint2* csr = nullptr;
  u16* xl1 = (u16*)alloc((size_t)NN * 32);
  u16* xr1 = (u16*)alloc((size_t)NN * 32);
  u16* hp1 = (u16*)alloc((size_t)NN * 32);
  u16* agg = (u16*)alloc((size_t)NN * 32);
  int tier3 = 0;
  if (off * sizeof(float) > ws_size) {
    tier3 = 1;
    off = zoff;
    start   = (int*)alloc(NN + 1);
    cursor  = (int*)alloc(NN);
    csr     = (uint2*)alloc((size_t)ETOT * 2);
    ea16    = nullptr;
    xl1 = (u16*)alloc((size_t)NN * 32);
    xr1 = (u16*)alloc((size_t)NN * 32);
    hp1 = (u16*)alloc((size_t)NN * 32);
    agg = (u16*)alloc((size_t)NN * 32);
  }
  u16* h1  = xr1;
  u16* xl2 = xl1;
  u16* xr2 = xl1 + (size_t)NN * 32;
  u16* hp2 = hp1;

  int eg = (ETOT + 255) / 256;

  // D1: zero + detect
  k_init<<<128, 256, 0, stream>>>((uint4*)d_ws, (int)zcnt16,
                                  (const unsigned*)x, (const unsigned*)skip1_W,
                                  (const unsigned*)eattr, flags);
  // D2: hist + colsum + last-block scan
  k_histscan<<<eg, 256, 0, stream>>>(ei, eattr, deg, mean_sums, start, cursor, done_hs);
  // D3: CSR build || lin3 L1
  k_buildlin1<128, 64><<<eg + 375, 256, 0, stream>>>(
      eg, tier3, ei, eattr, flags, mean_sums, cursor, csr_src, ea16, csr,
      x, c1_Wl, c1_Wr, skip1_W, c1_bl, c1_br, skip1_b, xl1, xr1, hp1, NN);
  // D4: fused L1 (+bn tail)
  if (!tier3) {
    k_fusedp<2, 32><<<NN / 4, 256, 0, stream>>>(start, csr_src, ea16, flags,
                                                xl1, xr1, c1_We, c1_att, agg,
                                                slots_s1, slots_q1, bnsum1, bnsq1, done_f1);
  } else {
    k_fusedg<2, 32><<<NN / 4, 256, 0, stream>>>(start, csr, eattr, flags, mean_sums,
                                                xl1, xr1, c1_We, c1_att, agg,
                                                slots_s1, slots_q1, bnsum1, bnsq1, done_f1);
  }
  // D5: bn apply L1
  k_bnapply<64><<<(NN * 64 + 255) / 256, 256, 0, stream>>>(agg, hp1, bnsum1, bnsq1,
                                                           bn1_g, bn1_b, flags, h1, NN);
  // D6: lin3 L2
  {
    dim3 g(125, 3);
    k_lin3b<64, 32><<<g, 256, 0, stream>>>(h1, flags, c2_Wl, c2_Wr, skip2_W,
                                           c2_bl, c2_br, skip2_b,
                                           xl2, xr2, hp2, NN);
  }
  // D7: fused L2 (+bn tail)
  if (!tier3) {
    k_fusedp<1, 32><<<NN / 8, 256, 0, stream>>>(start, csr_src, ea16, flags,
                                                xl2, xr2, c2_We, c2_att, agg,
                                                slots_s2, slots_q2, bnsum2, bnsq2, done_f2);
  } else {
    k_fusedg<1, 32><<<NN / 8, 256, 0, stream>>>(start, csr, eattr, flags, mean_sums,
                                                xl2, xr2, c2_We, c2_att, agg,
                                                slots_s2, slots_q2, bnsum2, bnsq2, done_f2);
  }
  // D8: bn2 apply + pool + finalize
  k_poolall<<<(NN + 255) / 256, 256, 0, stream>>>(agg, hp2, bnsum2, bnsq2,
                                                  bn2_g, bn2_b, flags, batch,
                                                  pool_sum, pool_maxk, pool_cnt,
                                                  done_pool, d_out);
}

// Round 13
// 737.744 us; speedup vs baseline: 3.3913x; 3.3913x over previous
//
#include <hip/hip_runtime.h>
#include <hip/hip_bf16.h>

#define NE 800000
#define NN 50000
#define NG 16
#define ETOT (NE + NN)

typedef unsigned short u16;
typedef __attribute__((ext_vector_type(8))) short short8;
typedef __attribute__((ext_vector_type(4))) float float4v;

__device__ __forceinline__ float b2f(u16 u) {
  return __uint_as_float(((unsigned)u) << 16);
}
__device__ __forceinline__ u16 f2b(float f) {
  __hip_bfloat16 b = __float2bfloat16(f);
  return *(u16*)&b;
}
__device__ __forceinline__ void cv8(uint4 v, float* o) {
  o[0] = __uint_as_float(v.x << 16);
  o[1] = __uint_as_float(v.x & 0xFFFF0000u);
  o[2] = __uint_as_float(v.y << 16);
  o[3] = __uint_as_float(v.y & 0xFFFF0000u);
  o[4] = __uint_as_float(v.z << 16);
  o[5] = __uint_as_float(v.z & 0xFFFF0000u);
  o[6] = __uint_as_float(v.w << 16);
  o[7] = __uint_as_float(v.w & 0xFFFF0000u);
}
__device__ __forceinline__ unsigned pk2(float a, float b) {
  return (unsigned)f2b(a) | ((unsigned)f2b(b) << 16);
}
__device__ __forceinline__ unsigned f2key(float f) {
  unsigned u = __float_as_uint(f);
  return (u & 0x80000000u) ? ~u : (u | 0x80000000u);
}
__device__ __forceinline__ float key2f(unsigned k) {
  unsigned u = (k & 0x80000000u) ? (k ^ 0x80000000u) : ~k;
  return __uint_as_float(u);
}
__device__ __forceinline__ int plaus(unsigned h) {
  unsigned eh = (h >> 7) & 0xFF;
  return (h == 0) || (eh >= 100 && eh <= 140);
}

// ========== D1: zero accumulator region + dtype detect (block 0; NO fence) ==========
__global__ __launch_bounds__(256) void k_init(uint4* __restrict__ zbase, int zcnt16,
                                              const unsigned* __restrict__ a,
                                              const unsigned* __restrict__ b,
                                              const unsigned* __restrict__ c,
                                              int* __restrict__ flags) {
  uint4 z = {0, 0, 0, 0};
  for (int i = blockIdx.x * 256 + threadIdx.x; i < zcnt16; i += gridDim.x * 256)
    zbase[i] = z;
  if (blockIdx.x != 0) return;
  __shared__ int cnt[3];
  if (threadIdx.x < 3) cnt[threadIdx.x] = 0;
  __syncthreads();
  const unsigned* arr[3] = {a, b, c};
  for (int k = 0; k < 3; k++) {
    int ok = 0;
    for (int i = threadIdx.x; i < 4096; i += 256) {
      unsigned w = arr[k][i];
      ok += (plaus(w & 0xFFFFu) && plaus(w >> 16)) ? 1 : 0;
    }
    atomicAdd(&cnt[k], ok);
  }
  __syncthreads();
  if (threadIdx.x == 0) {
    int f0 = cnt[0] > 2048, f1 = cnt[1] > 2048, f2 = cnt[2] > 2048;
    flags[0] = f0;
    flags[1] = f1;
    flags[2] = f2;
    flags[3] = f0 && f1 && f2;
  }
}

// ========== D2: dst-degree histogram + edge_attr column sums (NO fence) ==========
__global__ __launch_bounds__(256) void k_histcol(const int* __restrict__ ei,
                                                 const void* __restrict__ ea,
                                                 const int* __restrict__ flg,
                                                 int* __restrict__ deg,
                                                 float* __restrict__ sums) {
  int gt = blockIdx.x * 256 + threadIdx.x;
  if (gt < ETOT) {
    int dst = (gt < NE) ? ei[NE + gt] : gt - NE;
    atomicAdd(&deg[dst], 1);
  }
  bool eb = flg[2] != 0;
  int col = gt & 15;
  int row = gt >> 4;
  int rstride = (gridDim.x * 256) >> 4;
  float s = 0.f;
  if (eb) {
    const u16* p = (const u16*)ea;
    for (int e = row; e < NE; e += rstride) s += b2f(p[(size_t)e * 16 + col]);
  } else {
    const float* p = (const float*)ea;
    for (int e = row; e < NE; e += rstride) s += p[(size_t)e * 16 + col];
  }
  __shared__ float ls[256];
  ls[threadIdx.x] = s;
  __syncthreads();
  if (threadIdx.x < 16) {
    float t = 0.f;
    for (int i = threadIdx.x; i < 256; i += 16) t += ls[i];
    atomicAdd(&sums[threadIdx.x], t);
  }
}

// ========== D3: prefix scan (block 375) || lin3 layer-1 (blocks 0..374) ==========
template <int K, int N>
__global__ __launch_bounds__(256) void k_scanlin1(
    const int* __restrict__ deg, int* __restrict__ start, int* __restrict__ cursor,
    const void* __restrict__ xin, const int* __restrict__ flg,
    const void* W0, const void* W1, const void* W2,
    const void* b0, const void* b1, const void* b2,
    u16* __restrict__ o0, u16* __restrict__ o1, u16* __restrict__ o2, int M) {
  constexpr int TM = 32;
  constexpr size_t SMV = (size_t)(K * N + TM * (K + 1) + N) * 4;
  constexpr size_t SMM = (size_t)K * N * 2;
  __shared__ __align__(16) char smem[SMV > SMM ? SMV : SMM];

  if ((int)blockIdx.x == 375) {
    // ---- prefix scan over deg (plain reads; prior-dispatch writes visible) ----
    int* ps = (int*)smem;
    int t = threadIdx.x;
    const int CH = (NN + 255) / 256;
    int b0i = t * CH;
    int bend = min(b0i + CH, NN);
    int s = 0;
    for (int i = b0i; i < bend; i++) s += deg[i];
    ps[t] = s;
    __syncthreads();
    for (int ofs = 1; ofs < 256; ofs <<= 1) {
      int v = (t >= ofs) ? ps[t - ofs] : 0;
      __syncthreads();
      ps[t] += v;
      __syncthreads();
    }
    int run = (t == 0) ? 0 : ps[t - 1];
    for (int i = b0i; i < bend; i++) {
      start[i] = run;
      cursor[i] = run;
      run += deg[i];
    }
    if (t == 255) start[NN] = run;
    return;
  }
  // ---- lin3 L1 ----
  int lidx = blockIdx.x;      // 0..374
  int wset = lidx / 125;
  int tile = lidx % 125;
  bool wb = flg[1] != 0;
  bool xb = flg[0] != 0;
  const void* W = wset == 0 ? W0 : (wset == 1 ? W1 : W2);
  const void* bb = wset == 0 ? b0 : (wset == 1 ? b1 : b2);
  u16* out = wset == 0 ? o0 : (wset == 1 ? o1 : o2);

  if (wb && xb) {
    constexpr int CT = N / 16;
    constexpr int WPC = 4 / CT;
    constexpr int KK = K / 32;
    const u16* Wp = (const u16*)W;
    const u16* bp = (const u16*)bb;
    const u16* xp = (const u16*)xin;
    u16* Wl = (u16*)smem;
    for (int i = threadIdx.x; i < K * N / 8; i += 256)
      *(uint4*)&Wl[i * 8] = ((const uint4*)Wp)[i];
    __syncthreads();
    int wave = threadIdx.x >> 6;
    int lane = threadIdx.x & 63;
    int col = lane & 15;
    int quad = lane >> 4;
    int ct = wave % CT;
    int rt_off = wave / CT;
    short8 bfrag[KK];
#pragma unroll
    for (int kk = 0; kk < KK; kk++) {
      short8 t;
#pragma unroll
      for (int j = 0; j < 8; j++)
        t[j] = (short)Wl[(kk * 32 + quad * 8 + j) * N + ct * 16 + col];
      bfrag[kk] = t;
    }
    float bias = b2f(bp[ct * 16 + col]);
    constexpr int RPB = 25;
    int rt0 = tile * RPB;
    for (int i = rt_off; i < RPB; i += WPC) {
      int rt = rt0 + i;
      int row = rt * 16 + col;
      float4v acc = {0.f, 0.f, 0.f, 0.f};
#pragma unroll
      for (int kk = 0; kk < KK; kk++) {
        short8 afrag = *(const short8*)(xp + (size_t)row * K + kk * 32 + quad * 8);
        acc = __builtin_amdgcn_mfma_f32_16x16x32_bf16(afrag, bfrag[kk], acc, 0, 0, 0);
      }
#pragma unroll
      for (int r = 0; r < 4; r++) {
        int orow = rt * 16 + quad * 4 + r;
        out[(size_t)orow * N + ct * 16 + col] = f2b(acc[r] + bias);
      }
    }
  } else {
    constexpr int CPT = (N >= 64) ? 8 : 4;
    constexpr int TCOLS = N / CPT;
    float* Wf = (float*)smem;
    float* xs = Wf + K * N;
    float* bfs = xs + TM * (K + 1);
    int tid = threadIdx.x;
    if (wb) {
      const u16* Wp = (const u16*)W;
      for (int i = tid; i < K * N / 8; i += 256) {
        float t[8];
        cv8(*(const uint4*)(Wp + i * 8), t);
#pragma unroll
        for (int q = 0; q < 8; q++) Wf[i * 8 + q] = t[q];
      }
    } else {
      const float* Wp = (const float*)W;
      for (int i = tid; i < K * N / 4; i += 256) {
        float4 v = *(const float4*)(Wp + i * 4);
        Wf[i * 4 + 0] = v.x; Wf[i * 4 + 1] = v.y;
        Wf[i * 4 + 2] = v.z; Wf[i * 4 + 3] = v.w;
      }
    }
    if (tid < N) bfs[tid] = wb ? b2f(((const u16*)bb)[tid]) : ((const float*)bb)[tid];
    int tc = tid % TCOLS, tr = tid / TCOLS;
    for (int r0 = tile * TM; r0 < M; r0 += 125 * TM) {
      __syncthreads();
      if (xb) {
        const u16* xp = (const u16*)xin;
        for (int i = tid; i < TM * K / 8; i += 256) {
          int lr = i / (K / 8), lc = (i % (K / 8)) * 8;
          int gr = r0 + lr;
          float t[8] = {0, 0, 0, 0, 0, 0, 0, 0};
          if (gr < M) cv8(*(const uint4*)(xp + (size_t)gr * K + lc), t);
#pragma unroll
          for (int q = 0; q < 8; q++) xs[lr * (K + 1) + lc + q] = t[q];
        }
      } else {
        const float* xp = (const float*)xin;
        for (int i = tid; i < TM * K / 4; i += 256) {
          int lr = i / (K / 4), lc = (i % (K / 4)) * 4;
          int gr = r0 + lr;
          float4 v = {0, 0, 0, 0};
          if (gr < M) v = *(const float4*)(xp + (size_t)gr * K + lc);
          xs[lr * (K + 1) + lc + 0] = v.x;
          xs[lr * (K + 1) + lc + 1] = v.y;
          xs[lr * (K + 1) + lc + 2] = v.z;
          xs[lr * (K + 1) + lc + 3] = v.w;
        }
      }
      __syncthreads();
      float acc[CPT];
#pragma unroll
      for (int c = 0; c < CPT; c++) acc[c] = bfs[tc * CPT + c];
#pragma unroll 4
      for (int k = 0; k < K; k++) {
        float xv = xs[tr * (K + 1) + k];
#pragma unroll
        for (int c = 0; c < CPT; c++) acc[c] += xv * Wf[k * N + tc * CPT + c];
      }
      int gr = r0 + tr;
      if (gr < M) {
        u16* op = out + (size_t)gr * N + tc * CPT;
        if constexpr (CPT == 8) {
          uint4 o;
          o.x = pk2(acc[0], acc[1]); o.y = pk2(acc[2], acc[3]);
          o.z = pk2(acc[4], acc[5]); o.w = pk2(acc[6], acc[7]);
          *(uint4*)op = o;
        } else {
          uint2 o;
          o.x = pk2(acc[0], acc[1]); o.y = pk2(acc[2], acc[3]);
          *(uint2*)op = o;
        }
      }
    }
  }
}

// ========== D4: CSR build with bf16 payload (tier2) / eid-indirect (tier3) ==========
__global__ __launch_bounds__(256) void k_buildcsr_pay(
    const int* __restrict__ ei, const void* __restrict__ eattr,
    const int* __restrict__ flg, const float* __restrict__ mean_sums,
    int* __restrict__ cursor, int* __restrict__ csr_src,
    u16* __restrict__ ea16) {
  int e = blockIdx.x * 256 + threadIdx.x;
  if (e >= ETOT) return;
  bool eb = flg[2] != 0;
  int src, dst;
  if (e < NE) { src = ei[e]; dst = ei[NE + e]; } else { src = dst = e - NE; }
  float rec[16];
  if (e < NE) {
    if (eb) {
      const uint4* q = (const uint4*)((const u16*)eattr + (size_t)e * 16);
      cv8(q[0], rec);
      cv8(q[1], rec + 8);
    } else {
      const float* q = (const float*)eattr + (size_t)e * 16;
#pragma unroll
      for (int k = 0; k < 16; k++) rec[k] = q[k];
    }
  } else {
#pragma unroll
    for (int k = 0; k < 16; k++) rec[k] = mean_sums[k] * (1.0f / NE);
  }
  int pos = atomicAdd(&cursor[dst], 1);
  csr_src[pos] = src;
  u16 rb[16];
#pragma unroll
  for (int k = 0; k < 16; k++) rb[k] = f2b(rec[k]);
  uint4* dp = (uint4*)(ea16 + (size_t)pos * 16);
  dp[0] = *(uint4*)rb;
  dp[1] = *(uint4*)(rb + 8);
}

__global__ __launch_bounds__(256) void k_buildcsr(const int* __restrict__ ei,
                                                  int* __restrict__ cursor,
                                                  uint2* __restrict__ csr) {
  int e = blockIdx.x * 256 + threadIdx.x;
  if (e >= ETOT) return;
  int src, dst;
  if (e < NE) { src = ei[e]; dst = ei[NE + e]; } else { src = dst = e - NE; }
  int pos = atomicAdd(&cursor[dst], 1);
  uint2 r; r.x = (unsigned)src; r.y = (unsigned)e;
  csr[pos] = r;
}

// ==== standalone lin3 (layer 2) ====
template <int K, int N>
__global__ __launch_bounds__(256) void k_lin3b(
    const void* __restrict__ xin, const int* __restrict__ flg,
    const void* W0, const void* W1, const void* W2,
    const void* b0, const void* b1, const void* b2,
    u16* __restrict__ o0, u16* __restrict__ o1, u16* __restrict__ o2, int M) {
  constexpr int TM = 32;
  constexpr size_t SMV = (size_t)(K * N + TM * (K + 1) + N) * 4;
  constexpr size_t SMM = (size_t)K * N * 2;
  __shared__ __align__(16) char smem[SMV > SMM ? SMV : SMM];
  bool wb = flg[1] != 0;
  const void* W = blockIdx.y == 0 ? W0 : (blockIdx.y == 1 ? W1 : W2);
  const void* bb = blockIdx.y == 0 ? b0 : (blockIdx.y == 1 ? b1 : b2);
  u16* out = blockIdx.y == 0 ? o0 : (blockIdx.y == 1 ? o1 : o2);
  if (wb) {
    constexpr int CT = N / 16;
    constexpr int WPC = 4 / CT;
    constexpr int KK = K / 32;
    const u16* Wp = (const u16*)W;
    const u16* bp = (const u16*)bb;
    const u16* xp = (const u16*)xin;
    u16* Wl = (u16*)smem;
    for (int i = threadIdx.x; i < K * N / 8; i += 256)
      *(uint4*)&Wl[i * 8] = ((const uint4*)Wp)[i];
    __syncthreads();
    int wave = threadIdx.x >> 6;
    int lane = threadIdx.x & 63;
    int col = lane & 15;
    int quad = lane >> 4;
    int ct = wave % CT;
    int rt_off = wave / CT;
    short8 bfrag[KK];
#pragma unroll
    for (int kk = 0; kk < KK; kk++) {
      short8 t;
#pragma unroll
      for (int j = 0; j < 8; j++)
        t[j] = (short)Wl[(kk * 32 + quad * 8 + j) * N + ct * 16 + col];
      bfrag[kk] = t;
    }
    float bias = b2f(bp[ct * 16 + col]);
    constexpr int RPB = 25;
    int rt0 = blockIdx.x * RPB;
    for (int i = rt_off; i < RPB; i += WPC) {
      int rt = rt0 + i;
      int row = rt * 16 + col;
      float4v acc = {0.f, 0.f, 0.f, 0.f};
#pragma unroll
      for (int kk = 0; kk < KK; kk++) {
        short8 afrag = *(const short8*)(xp + (size_t)row * K + kk * 32 + quad * 8);
        acc = __builtin_amdgcn_mfma_f32_16x16x32_bf16(afrag, bfrag[kk], acc, 0, 0, 0);
      }
#pragma unroll
      for (int r = 0; r < 4; r++) {
        int orow = rt * 16 + quad * 4 + r;
        out[(size_t)orow * N + ct * 16 + col] = f2b(acc[r] + bias);
      }
    }
  } else {
    constexpr int CPT = 4;
    constexpr int TCOLS = N / CPT;
    float* Wf = (float*)smem;
    float* xs = Wf + K * N;
    float* bfs = xs + TM * (K + 1);
    int tid = threadIdx.x;
    {
      const float* Wp = (const float*)W;
      for (int i = tid; i < K * N / 4; i += 256) {
        float4 v = *(const float4*)(Wp + i * 4);
        Wf[i * 4 + 0] = v.x; Wf[i * 4 + 1] = v.y;
        Wf[i * 4 + 2] = v.z; Wf[i * 4 + 3] = v.w;
      }
    }
    if (tid < N) bfs[tid] = ((const float*)bb)[tid];
    int tc = tid % TCOLS, tr = tid / TCOLS;
    for (int r0 = blockIdx.x * TM; r0 < M; r0 += gridDim.x * TM) {
      __syncthreads();
      const u16* xp = (const u16*)xin;
      for (int i = tid; i < TM * K / 8; i += 256) {
        int lr = i / (K / 8), lc = (i % (K / 8)) * 8;
        int gr = r0 + lr;
        float t[8] = {0, 0, 0, 0, 0, 0, 0, 0};
        if (gr < M) cv8(*(const uint4*)(xp + (size_t)gr * K + lc), t);
#pragma unroll
        for (int q = 0; q < 8; q++) xs[lr * (K + 1) + lc + q] = t[q];
      }
      __syncthreads();
      float acc[CPT];
#pragma unroll
      for (int c = 0; c < CPT; c++) acc[c] = bfs[tc * CPT + c];
#pragma unroll 4
      for (int k = 0; k < K; k++) {
        float xv = xs[tr * (K + 1) + k];
#pragma unroll
        for (int c = 0; c < CPT; c++) acc[c] += xv * Wf[k * N + tc * CPT + c];
      }
      int gr = r0 + tr;
      if (gr < M) {
        uint2 o;
        o.x = pk2(acc[0], acc[1]); o.y = pk2(acc[2], acc[3]);
        *(uint2*)(out + (size_t)gr * N + tc * CPT) = o;
      }
    }
  }
}

// ===== payload dots =====
__device__ __forceinline__ float dot16b(const u16* __restrict__ p,
                                        const float* __restrict__ W) {
  float ea[16];
  const uint4* q = (const uint4*)p;
  cv8(q[0], ea);
  cv8(q[1], ea + 8);
  float s = 0.f;
#pragma unroll
  for (int k = 0; k < 16; k++) s += ea[k] * W[k];
  return s;
}
__device__ __forceinline__ float dot16f(const float* __restrict__ q,
                                        const float* __restrict__ W) {
  float s = 0.f;
#pragma unroll
  for (int k = 0; k < 16; k++) s += q[k] * W[k];
  return s;
}

// ===== D5/D9: fused attention + softmax gather-reduce (bf16 payload, NO fence) =====
template <int H, int C>
__global__ __launch_bounds__(256) void k_fusedp(
    const int* __restrict__ start, const int* __restrict__ csr_src,
    const u16* __restrict__ pay, const int* __restrict__ flg,
    const u16* __restrict__ xl, const u16* __restrict__ xr,
    const void* We, const void* att, u16* __restrict__ agg) {
  constexpr int D = H * C;
  constexpr int NPW = 64 / D;
  bool wb = flg[1] != 0;
  int lane = threadIdx.x & 63;
  int ch = lane % D;
  float Wreg[16];
  if (wb) {
    const u16* Wp = (const u16*)We;
#pragma unroll
    for (int k = 0; k < 16; k++) Wreg[k] = b2f(Wp[k * D + ch]);
  } else {
    const float* Wp = (const float*)We;
#pragma unroll
    for (int k = 0; k < 16; k++) Wreg[k] = Wp[k * D + ch];
  }
  float attv = wb ? b2f(((const u16*)att)[ch]) : ((const float*)att)[ch];
  int wid = (blockIdx.x * 256 + threadIdx.x) >> 6;
  int node = wid * NPW + lane / D;   // grids exact: node < NN always
  int s0 = start[node], s1 = start[node + 1];
  float xrv = b2f(xr[(size_t)node * D + ch]);
  float ssum = 0.f, acc = 0.f;

  if constexpr (NPW == 1) {
    // deg is wave-uniform: guard-free pair loop + tail
    int p = s0;
    for (; p + 1 < s1; p += 2) {
      int c0 = csr_src[p], c1 = csr_src[p + 1];
      float xlv0 = b2f(xl[(size_t)c0 * D + ch]);
      float xlv1 = b2f(xl[(size_t)c1 * D + ch]);
      float ev0 = dot16b(pay + (size_t)p * 16, Wreg);
      float ev1 = dot16b(pay + (size_t)(p + 1) * 16, Wreg);
      float mv0 = xlv0 + xrv + ev0;
      float mv1 = xlv1 + xrv + ev1;
      mv0 = (mv0 > 0.f) ? mv0 : 0.2f * mv0;
      mv1 = (mv1 > 0.f) ? mv1 : 0.2f * mv1;
      float t0 = mv0 * attv, t1 = mv1 * attv;
#pragma unroll
      for (int mk = 1; mk <= 16; mk <<= 1) {
        t0 += __shfl_xor(t0, mk, 64);
        t1 += __shfl_xor(t1, mk, 64);
      }
      float ex0 = __expf(t0);
      float ex1 = __expf(t1);
      ssum += ex0 + ex1;
      acc += ex0 * xlv0 + ex1 * xlv1;
    }
    if (p < s1) {
      int c0 = csr_src[p];
      float xlv = b2f(xl[(size_t)c0 * D + ch]);
      float ev = dot16b(pay + (size_t)p * 16, Wreg);
      float mv = xlv + xrv + ev;
      mv = (mv > 0.f) ? mv : 0.2f * mv;
      float t = mv * attv;
#pragma unroll
      for (int mk = 1; mk <= 16; mk <<= 1) t += __shfl_xor(t, mk, 64);
      float ex = __expf(t);
      ssum += ex;
      acc += ex * xlv;
    }
  } else {
    int deg = s1 - s0;
    int last = s1 - 1;
    int degmax = max(deg, __shfl_xor(deg, 32, 64));
    for (int i = 0; i < degmax; i += 2) {
      int p0 = min(s0 + i, last), p1 = min(s0 + i + 1, last);
      bool a0 = i < deg, a1 = i + 1 < deg;
      int c0 = csr_src[p0], c1 = csr_src[p1];
      float xlv0 = b2f(xl[(size_t)c0 * D + ch]);
      float xlv1 = b2f(xl[(size_t)c1 * D + ch]);
      float ev0 = dot16b(pay + (size_t)p0 * 16, Wreg);
      float ev1 = dot16b(pay + (size_t)p1 * 16, Wreg);
      float mv0 = xlv0 + xrv + ev0;
      float mv1 = xlv1 + xrv + ev1;
      mv0 = (mv0 > 0.f) ? mv0 : 0.2f * mv0;
      mv1 = (mv1 > 0.f) ? mv1 : 0.2f * mv1;
      float t0 = mv0 * attv, t1 = mv1 * attv;
#pragma unroll
      for (int mk = 1; mk <= 16; mk <<= 1) {
        t0 += __shfl_xor(t0, mk, 64);
        t1 += __shfl_xor(t1, mk, 64);
      }
      float ex0 = a0 ? __expf(t0) : 0.f;
      float ex1 = a1 ? __expf(t1) : 0.f;
      ssum += ex0 + ex1;
      acc += ex0 * xlv0 + ex1 * xlv1;
    }
  }
  agg[(size_t)node * D + ch] = f2b(acc / (ssum + 1e-16f));
}

// ===== tier-3 eid-indirect fused =====
template <int H, int C>
__global__ __launch_bounds__(256) void k_fusedg(
    const int* __restrict__ start, const uint2* __restrict__ csr,
    const void* __restrict__ eattr, const int* __restrict__ flg,
    const float* __restrict__ mean_sums,
    const u16* __restrict__ xl, const u16* __restrict__ xr,
    const void* We, const void* att, u16* __restrict__ agg) {
  constexpr int D = H * C;
  constexpr int NPW = 64 / D;
  bool wb = flg[1] != 0;
  bool eb = flg[2] != 0;
  int lane = threadIdx.x & 63;
  int ch = lane % D;
  float Wreg[16];
  if (wb) {
    const u16* Wp = (const u16*)We;
#pragma unroll
    for (int k = 0; k < 16; k++) Wreg[k] = b2f(Wp[k * D + ch]);
  } else {
    const float* Wp = (const float*)We;
#pragma unroll
    for (int k = 0; k < 16; k++) Wreg[k] = Wp[k * D + ch];
  }
  float attv = wb ? b2f(((const u16*)att)[ch]) : ((const float*)att)[ch];
  float ev_self = 0.f;
#pragma unroll
  for (int k = 0; k < 16; k++) ev_self += mean_sums[k] * (1.0f / NE) * Wreg[k];
  int wid = (blockIdx.x * 256 + threadIdx.x) >> 6;
  int node = wid * NPW + lane / D;
  int s0 = start[node], s1 = start[node + 1];
  int deg = s1 - s0;
  int last = s1 - 1;
  int degmax = deg;
  if constexpr (NPW == 2) degmax = max(deg, __shfl_xor(deg, 32, 64));
  float xrv = b2f(xr[(size_t)node * D + ch]);
  float ssum = 0.f, acc = 0.f;
  for (int i = 0; i < degmax; i += 2) {
    uint2 cr0 = csr[min(s0 + i, last)];
    uint2 cr1 = csr[min(s0 + i + 1, last)];
    bool a0 = i < deg, a1 = i + 1 < deg;
    float xlv0 = b2f(xl[(size_t)cr0.x * D + ch]);
    float xlv1 = b2f(xl[(size_t)cr1.x * D + ch]);
    float ev0 = cr0.y < NE ? (eb ? dot16b((const u16*)eattr + (size_t)cr0.y * 16, Wreg)
                                 : dot16f((const float*)eattr + (size_t)cr0.y * 16, Wreg))
                           : ev_self;
    float ev1 = cr1.y < NE ? (eb ? dot16b((const u16*)eattr + (size_t)cr1.y * 16, Wreg)
                                 : dot16f((const float*)eattr + (size_t)cr1.y * 16, Wreg))
                           : ev_self;
    float mv0 = xlv0 + xrv + ev0;
    float mv1 = xlv1 + xrv + ev1;
    mv0 = (mv0 > 0.f) ? mv0 : 0.2f * mv0;
    mv1 = (mv1 > 0.f) ? mv1 : 0.2f * mv1;
    float t0 = mv0 * attv, t1 = mv1 * attv;
#pragma unroll
    for (int mk = 1; mk <= 16; mk <<= 1) {
      t0 += __shfl_xor(t0, mk, 64);
      t1 += __shfl_xor(t1, mk, 64);
    }
    float ex0 = a0 ? __expf(t0) : 0.f;
    float ex1 = a1 ? __expf(t1) : 0.f;
    ssum += ex0 + ex1;
    acc += ex0 * xlv0 + ex1 * xlv1;
  }
  agg[(size_t)node * D + ch] = f2b(acc / (ssum + 1e-16f));
}

// ========== batch-norm reduce (separate kernel, grid 256, NO fence) ==========
template <int D>
__global__ __launch_bounds__(256) void k_bnred(const u16* __restrict__ v,
                                               float* __restrict__ sum,
                                               float* __restrict__ sq, int M) {
  constexpr int RB = 256 / D;
  int tid = threadIdx.x;
  int c = tid % D;
  int rg = tid / D;
  float s = 0.f, q = 0.f;
  for (int r = blockIdx.x * RB + rg; r < M; r += gridDim.x * RB) {
    float x = b2f(v[(size_t)r * D + c]);
    s += x;
    q += x * x;
  }
  __shared__ float ls[256], lq[256];
  ls[tid] = s; lq[tid] = q;
  __syncthreads();
  if (tid < D) {
    float ts = 0.f, tq = 0.f;
    for (int i = tid; i < 256; i += D) { ts += ls[i]; tq += lq[i]; }
    atomicAdd(&sum[tid], ts);
    atomicAdd(&sq[tid], tq);
  }
}

// ========== batch-norm apply + skip + ELU (layer 1) ==========
template <int D>
__global__ __launch_bounds__(256) void k_bnapply(const u16* __restrict__ agg,
                                                 const u16* __restrict__ hp,
                                                 const float* __restrict__ sum,
                                                 const float* __restrict__ sq,
                                                 const void* g, const void* b,
                                                 const int* __restrict__ flg,
                                                 u16* __restrict__ out, int M) {
  bool wb = flg[1] != 0;
  int idx = blockIdx.x * 256 + threadIdx.x;
  if (idx >= M * D) return;
  int c = idx & (D - 1);
  float gc = wb ? b2f(((const u16*)g)[c]) : ((const float*)g)[c];
  float bc = wb ? b2f(((const u16*)b)[c]) : ((const float*)b)[c];
  float mu = sum[c] * (1.f / M);
  float var = fmaxf(sq[c] * (1.f / M) - mu * mu, 0.f);
  float sc = rsqrtf(var + 1e-5f) * gc;
  float v = (b2f(agg[idx]) - mu) * sc + bc + b2f(hp[idx]);
  v = v > 0.f ? v : expm1f(v);
  out[idx] = f2b(v);
}

// ========== D11: BN2-apply + ELU + pool + (last block) finalize ==========
// 196 blocks: the ONLY fence-based pattern (proven cheap at this block count).
__global__ __launch_bounds__(256) void k_poolall(
    const u16* __restrict__ agg2, const u16* __restrict__ hp2,
    const float* __restrict__ sum, const float* __restrict__ sq,
    const void* g, const void* b, const int* __restrict__ flg,
    const int* __restrict__ batch,
    float* __restrict__ pool_sum, unsigned* __restrict__ pool_maxk,
    float* __restrict__ pool_cnt, int* __restrict__ done_cnt,
    void* __restrict__ out) {
  bool wb = flg[1] != 0;
  int c = threadIdx.x & 31;
  int rg = threadIdx.x >> 5;
  float gc = wb ? b2f(((const u16*)g)[c]) : ((const float*)g)[c];
  float bc = wb ? b2f(((const u16*)b)[c]) : ((const float*)b)[c];
  float mu = sum[c] * (1.f / NN);
  float var = fmaxf(sq[c] * (1.f / NN) - mu * mu, 0.f);
  float scl = rsqrtf(var + 1e-5f) * gc;
  float sh = bc - mu * scl;

  const int NPB = 256;
  int n0 = blockIdx.x * NPB;
  int nend = min(n0 + NPB, NN);
  int cur = -1;
  float s = 0.f, mx = 0.f;
  int cnt = 0;
  for (int n = n0 + rg; n < nend; n += 8) {
    int gi = batch[n];
    float v = b2f(agg2[(size_t)n * 32 + c]) * scl + sh + b2f(hp2[(size_t)n * 32 + c]);
    v = v > 0.f ? v : expm1f(v);
    if (gi != cur) {
      if (cur >= 0) {
        atomicAdd(&pool_sum[cur * 32 + c], s);
        atomicMax(&pool_maxk[cur * 32 + c], f2key(mx));
        if (c == 0) atomicAdd(&pool_cnt[cur], (float)cnt);
      }
      cur = gi; s = 0.f; mx = -INFINITY; cnt = 0;
    }
    s += v;
    mx = fmaxf(mx, v);
    cnt++;
  }
  if (cur >= 0) {
    atomicAdd(&pool_sum[cur * 32 + c], s);
    atomicMax(&pool_maxk[cur * 32 + c], f2key(mx));
    if (c == 0) atomicAdd(&pool_cnt[cur], (float)cnt);
  }
  __threadfence();
  __syncthreads();
  __shared__ int lastblk;
  if (threadIdx.x == 0) lastblk = (atomicAdd(done_cnt, 1) == (int)gridDim.x - 1);
  __syncthreads();
  if (!lastblk) return;
  bool ob = flg[3] != 0;
  for (int idx = threadIdx.x; idx < NG * 64; idx += 256) {
    int gi = idx / 64, cc = idx % 64;
    float cntv = atomicAdd(&pool_cnt[gi], 0.f);
    float val;
    if (cc < 32) val = atomicAdd(&pool_sum[gi * 32 + cc], 0.f) / fmaxf(cntv, 1.f);
    else {
      unsigned k = atomicMax(&pool_maxk[gi * 32 + (cc - 32)], 0u);
      val = cntv > 0.f ? key2f(k) : 0.f;
    }
    if (ob) ((u16*)out)[idx] = f2b(val);
    else ((float*)out)[idx] = val;
  }
}

extern "C" void kernel_launch(void* const* d_in, const int* in_sizes, int n_in,
                              void* d_out, int out_size, void* d_ws, size_t ws_size,
                              hipStream_t stream) {
  (void)in_sizes; (void)n_in; (void)out_size;
  const void* x     = d_in[0];
  const int*  ei    = (const int*)d_in[1];
  const void* eattr = d_in[2];
  const int*  batch = (const int*)d_in[3];
  const void* skip1_W = d_in[4];
  const void* skip1_b = d_in[5];
  const void* c1_Wl = d_in[6];
  const void* c1_bl = d_in[7];
  const void* c1_Wr = d_in[8];
  const void* c1_br = d_in[9];
  const void* c1_We = d_in[10];
  const void* c1_att = d_in[11];
  const void* bn1_g = d_in[13];
  const void* bn1_b = d_in[14];
  const void* skip2_W = d_in[15];
  const void* skip2_b = d_in[16];
  const void* c2_Wl = d_in[17];
  const void* c2_bl = d_in[18];
  const void* c2_Wr = d_in[19];
  const void* c2_br = d_in[20];
  const void* c2_We = d_in[21];
  const void* c2_att = d_in[22];
  const void* bn2_g = d_in[24];
  const void* bn2_b = d_in[25];

  float* ws = (float*)d_ws;
  size_t off = 0;
  auto alloc = [&](size_t nfl) {
    float* p = ws + off;
    off += (nfl + 15) & ~(size_t)15;
    return p;
  };
  // ---- zero-initialized region ----
  int*   flags      = (int*)alloc(16);
  float* mean_sums  = alloc(16);
  int*   deg        = (int*)alloc(NN);
  float* bnsum1     = alloc(64);
  float* bnsq1      = alloc(64);
  float* bnsum2     = alloc(32);
  float* bnsq2      = alloc(32);
  float* pool_cnt   = alloc(NG);
  float* pool_sum   = alloc(NG * 32);
  unsigned* pool_maxk = (unsigned*)alloc(NG * 32);
  int*   done_pool  = (int*)alloc(16);
  size_t zcnt16 = (off * sizeof(float)) / 16;  // allocs 64B-granular
  size_t zoff = off;

  // ---- tier 2 layout (bf16 payload in CSR order, ~57 MB; proven to fit) ----
  int* start   = (int*)alloc(NN + 1);
  int* cursor  = (int*)alloc(NN);
  int* csr_src = (int*)alloc(ETOT);
  u16* ea16    = (u16*)alloc((size_t)ETOT * 8);
  uint2* csr = nullptr;
  u16* xl1 = (u16*)alloc((size_t)NN * 32);
  u16* xr1 = (u16*)alloc((size_t)NN * 32);
  u16* hp1 = (u16*)alloc((size_t)NN * 32);
  u16* agg = (u16*)alloc((size_t)NN * 32);
  int tier3 = 0;
  if (off * sizeof(float) > ws_size) {
    tier3 = 1;
    off = zoff;
    start   = (int*)alloc(NN + 1);
    cursor  = (int*)alloc(NN);
    csr     = (uint2*)alloc((size_t)ETOT * 2);
    ea16    = nullptr;
    xl1 = (u16*)alloc((size_t)NN * 32);
    xr1 = (u16*)alloc((size_t)NN * 32);
    hp1 = (u16*)alloc((size_t)NN * 32);
    agg = (u16*)alloc((size_t)NN * 32);
  }
  u16* h1  = xr1;
  u16* xl2 = xl1;
  u16* xr2 = xl1 + (size_t)NN * 32;
  u16* hp2 = hp1;

  int eg = (ETOT + 255) / 256;

  // D1: zero + detect
  k_init<<<128, 256, 0, stream>>>((uint4*)d_ws, (int)zcnt16,
                                  (const unsigned*)x, (const unsigned*)skip1_W,
                                  (const unsigned*)eattr, flags);
  // D2: hist + colsum
  k_histcol<<<eg, 256, 0, stream>>>(ei, eattr, flags, deg, mean_sums);
  // D3: scan (block 375) || lin3 L1 (blocks 0..374)
  k_scanlin1<128, 64><<<376, 256, 0, stream>>>(
      deg, start, cursor, x, flags, c1_Wl, c1_Wr, skip1_W,
      c1_bl, c1_br, skip1_b, xl1, xr1, hp1, NN);
  // D4: CSR build
  if (!tier3) {
    k_buildcsr_pay<<<eg, 256, 0, stream>>>(ei, eattr, flags, mean_sums,
                                           cursor, csr_src, ea16);
  } else {
    k_buildcsr<<<eg, 256, 0, stream>>>(ei, cursor, csr);
  }
  // D5: fused L1
  if (!tier3) {
    k_fusedp<2, 32><<<NN / 4, 256, 0, stream>>>(start, csr_src, ea16, flags,
                                                xl1, xr1, c1_We, c1_att, agg);
  } else {
    k_fusedg<2, 32><<<NN / 4, 256, 0, stream>>>(start, csr, eattr, flags, mean_sums,
                                                xl1, xr1, c1_We, c1_att, agg);
  }
  // D6: bnred L1
  k_bnred<64><<<256, 256, 0, stream>>>(agg, bnsum1, bnsq1, NN);
  // D7: bn apply L1
  k_bnapply<64><<<(NN * 64 + 255) / 256, 256, 0, stream>>>(agg, hp1, bnsum1, bnsq1,
                                                           bn1_g, bn1_b, flags, h1, NN);
  // D8: lin3 L2
  {
    dim3 g(125, 3);
    k_lin3b<64, 32><<<g, 256, 0, stream>>>(h1, flags, c2_Wl, c2_Wr, skip2_W,
                                           c2_bl, c2_br, skip2_b,
                                           xl2, xr2, hp2, NN);
  }
  // D9: fused L2
  if (!tier3) {
    k_fusedp<1, 32><<<NN / 8, 256, 0, stream>>>(start, csr_src, ea16, flags,
                                                xl2, xr2, c2_We, c2_att, agg);
  } else {
    k_fusedg<1, 32><<<NN / 8, 256, 0, stream>>>(start, csr, eattr, flags, mean_sums,
                                                xl2, xr2, c2_We, c2_att, agg);
  }
  // D10: bnred L2
  k_bnred<32><<<256, 256, 0, stream>>>(agg, bnsum2, bnsq2, NN);
  // D11: bn2 apply + pool + finalize
  k_poolall<<<(NN + 255) / 256, 256, 0, stream>>>(agg, hp2, bnsum2, bnsq2,
                                                  bn2_g, bn2_b, flags, batch,
                                                  pool_sum, pool_maxk, pool_cnt,
                                                  done_pool, d_out);
}